// Round 7
// baseline (301.697 us; speedup 1.0000x reference)
//
#include <hip/hip_runtime.h>
#include <hip/hip_bf16.h>
#include <math.h>

typedef __bf16 bf16_t;
typedef __bf16 bf16x4 __attribute__((ext_vector_type(4)));
typedef __bf16 bf16x8 __attribute__((ext_vector_type(8)));
typedef float floatx4 __attribute__((ext_vector_type(4)));
typedef unsigned int u32;

#define AS1 __attribute__((address_space(1)))
#define AS3 __attribute__((address_space(3)))

// Inputs fp32, output fp32.
__device__ bf16_t g_xb[8192 * 1024];              // x converted to bf16
__device__ bf16_t g_wqkvT[3072 * 1024];           // w_qkv^T (bf16)
__device__ bf16_t g_wprojT[1024 * 1024];          // w_proj^T (bf16)
__device__ float  g_bqkv[3072];
__device__ float  g_bproj[1024];
// Region 0: Q (bh, t, d) — reused as y after attention.
// Region 1: K (bh, t, d).
// Region 2: V^T (bh, d, t).
__device__ bf16_t g_qkv[3ull * 64 * 2048 * 64];
#define HBREG (64ull * 2048 * 64)

// ---------------- prep: x convert + both bias copies in one launch --------
__global__ __launch_bounds__(256) void cvt_x(const float* __restrict__ src,
                                             const float* __restrict__ bq,
                                             const float* __restrict__ bp) {
  int blk = blockIdx.x;
  int tid = threadIdx.x;
  if (blk < 4096) {
    int i0 = (blk * 256 + tid) * 8;
    const float4* s = (const float4*)src;
    float4 a = s[i0 / 4], b = s[i0 / 4 + 1];
    bf16x8 v;
    v[0] = (bf16_t)a.x; v[1] = (bf16_t)a.y; v[2] = (bf16_t)a.z; v[3] = (bf16_t)a.w;
    v[4] = (bf16_t)b.x; v[5] = (bf16_t)b.y; v[6] = (bf16_t)b.z; v[7] = (bf16_t)b.w;
    *(bf16x8*)&g_xb[i0] = v;
  } else if (blk == 4096) {
    for (int i = tid; i < 3072; i += 256) g_bqkv[i] = bq[i];
  } else {
    for (int i = tid; i < 1024; i += 256) g_bproj[i] = bp[i];
  }
}

// ---------------- 64x64 tiled transpose, both weights in one launch -------
__global__ __launch_bounds__(256) void tr64(const float* __restrict__ wqkv,
                                            const float* __restrict__ wproj) {
  __shared__ bf16_t tile[64][65];
  const int R = 1024;
  int bx = blockIdx.x;
  const float* in;
  bf16_t* out;
  int C, c0;
  if (bx < 48) { in = wqkv; out = g_wqkvT; C = 3072; c0 = bx * 64; }
  else         { in = wproj; out = g_wprojT; C = 1024; c0 = (bx - 48) * 64; }
  int r0 = blockIdx.y * 64;
  int tid = threadIdx.x;
#pragma unroll
  for (int it = 0; it < 16; ++it) {
    int idx = tid + it * 256;
    int r = idx >> 6, c = idx & 63;
    tile[r][c] = (bf16_t)in[(size_t)(r0 + r) * C + (c0 + c)];
  }
  __syncthreads();
#pragma unroll
  for (int it = 0; it < 16; ++it) {
    int idx = tid + it * 256;
    int r = idx >> 6, c = idx & 63;
    out[(size_t)(c0 + r) * R + (r0 + c)] = tile[c][r];
  }
}

// ------------- GEMM, m201 template: C = A @ Bt^T + bias -------------------
// R7 pipeline fix: ALL FOUR half-tile stages for kt+1 issued in one burst at
// kt.P1 (buffer (kt+1)&1 is safe there: its last reads ended at kt-1.P4
// before two barriers). Single vmcnt(0) at P4-end — the only loads in
// flight are kt+1's, issued ~3.5 phases (~1000 cy) earlier >= HBM latency.
// Replaces the R1 counted scheme whose min lookahead was 0-2 phases (the
// un-hidden staging latency measured as MfmaUtil 23% @ 88us).
#define MFMA16(a, b, c) __builtin_amdgcn_mfma_f32_16x16x32_bf16(a, b, c, 0, 0, 0)
#define SB0() __builtin_amdgcn_sched_barrier(0)
#define PH_MID()                                          \
  do {                                                    \
    SB0();                                                \
    __builtin_amdgcn_s_barrier();                         \
    SB0();                                                \
    asm volatile("s_waitcnt lgkmcnt(0)" ::: "memory");    \
    SB0();                                                \
  } while (0)
#define PH_END()                                          \
  do {                                                    \
    SB0();                                                \
    __builtin_amdgcn_s_barrier();                         \
    SB0();                                                \
  } while (0)

__global__ __launch_bounds__(512) void gemm256(float* __restrict__ out_ext,
                                               int M, int N, int K,
                                               int amode, int bsel, int cmode) {
  __shared__ alignas(16) bf16_t As[2][256 * 64];
  __shared__ alignas(16) bf16_t Bs[2][256 * 64];
  (void)M;
  const bf16_t* Ag = (amode == 0) ? g_xb : g_qkv;
  const bf16_t* Bt = bsel ? g_wprojT : g_wqkvT;
  const float* bias = bsel ? g_bproj : g_bqkv;
  const int tid = threadIdx.x;

  // XCD-aware bijective swizzle (nwg % 8 == 0 for both grids).
  int gx = gridDim.x;
  int nwg = gx * gridDim.y;
  int lin = blockIdx.y * gx + blockIdx.x;
  int swz = (lin & 7) * (nwg >> 3) + (lin >> 3);
  int bx = swz % gx, by = swz / gx;
  const int m0 = by * 256, n0 = bx * 256;

  const int lane = tid & 63, wave = tid >> 6;
  const int wm = wave >> 2, wn = wave & 3;      // 2M x 4N
  const int quad = lane >> 4, l16 = lane & 15;

  // ---- ds_read fragment addressing (swizzle: byte ^= (row&7)<<4) ----
  const u32 xv = (u32)(l16 & 7) << 4;
  const u32 sq0 = ((u32)quad * 16u) ^ xv;          // k-slab 0
  const u32 sq1 = (64u + (u32)quad * 16u) ^ xv;    // k-slab 1
  const u32 a_rb = (u32)(wm * 64 + l16) * 128u;    // + mh*16384 + mf*2048
  const u32 b_rb = (u32)(wn * 32 + l16) * 128u;    // + nh*16384 + nf*2048

  // ---- staging precompute: inverse-swizzled global source per thread ----
  u32 row_j[2], scol_j[2];
#pragma unroll
  for (int j = 0; j < 2; ++j) {
    u32 L = ((u32)j * 512u + (u32)tid) * 16u;   // LDS byte within 16KB half
    u32 y = L ^ (((L >> 7) & 7u) << 4);         // involution
    row_j[j] = y >> 7;                          // row 0..127 within half
    scol_j[j] = (y & 127u) >> 1;                // k elem 0..63
  }
  u32 a_go[2][2], b_go[2][2], akts;
  if (amode == 0) {
#pragma unroll
    for (int h = 0; h < 2; ++h)
#pragma unroll
      for (int j = 0; j < 2; ++j)
        a_go[h][j] = (u32)(m0 + h * 128 + (int)row_j[j]) * (u32)K + scol_j[j];
    akts = 64u;
  } else {
#pragma unroll
    for (int h = 0; h < 2; ++h)
#pragma unroll
      for (int j = 0; j < 2; ++j) {
        int m = m0 + h * 128 + (int)row_j[j];
        a_go[h][j] = (u32)(m >> 11) * 2097152u + (u32)(m & 2047) * 64u + scol_j[j];
      }
    akts = 131072u;   // K-tile == head stride in (bh,t,d) layout
  }
#pragma unroll
  for (int h = 0; h < 2; ++h)
#pragma unroll
    for (int j = 0; j < 2; ++j)
      b_go[h][j] = (u32)(n0 + h * 128 + (int)row_j[j]) * (u32)K + scol_j[j];

  auto stageA = [&](int kt_, int h_) {
#pragma unroll
    for (int j = 0; j < 2; ++j)
      __builtin_amdgcn_global_load_lds(
          (const AS1 void*)(Ag + (size_t)(a_go[h_][j] + (u32)kt_ * akts)),
          (AS3 void*)&As[kt_ & 1][h_ * 8192 + (j * 512 + tid) * 8], 16, 0, 0);
  };
  auto stageB = [&](int kt_, int h_) {
#pragma unroll
    for (int j = 0; j < 2; ++j)
      __builtin_amdgcn_global_load_lds(
          (const AS1 void*)(Bt + (size_t)(b_go[h_][j] + (u32)kt_ * 64u)),
          (AS3 void*)&Bs[kt_ & 1][h_ * 8192 + (j * 512 + tid) * 8], 16, 0, 0);
  };

  floatx4 acc[2][4][2][2] = {};   // [mh][mf][nh][nf]
  const int NT = K >> 6;

  // ---- prologue: stage all 4 halves of tile 0, drain, go ----
  stageA(0, 0); SB0(); stageB(0, 0); SB0();
  stageA(0, 1); SB0(); stageB(0, 1); SB0();
  asm volatile("s_waitcnt vmcnt(0)" ::: "memory");
  __builtin_amdgcn_s_barrier();
  SB0();

  for (int kt = 0; kt < NT; ++kt) {
    const int b = kt & 1;
    const char* Ab = (const char*)&As[b][0];
    const char* Bb = (const char*)&Bs[b][0];
    bf16x8 af[4][2], bv[2][2], bw[2][2];

    // ===== P1 (mh0,nh0): read A-h0 (8) + B-h0 (4); stage ALL of kt+1 =====
#pragma unroll
    for (int mf = 0; mf < 4; ++mf) {
      af[mf][0] = *(const bf16x8*)(Ab + (a_rb + mf * 2048 + sq0));
      af[mf][1] = *(const bf16x8*)(Ab + (a_rb + mf * 2048 + sq1));
    }
#pragma unroll
    for (int nf = 0; nf < 2; ++nf) {
      bv[nf][0] = *(const bf16x8*)(Bb + (b_rb + nf * 2048 + sq0));
      bv[nf][1] = *(const bf16x8*)(Bb + (b_rb + nf * 2048 + sq1));
    }
    if (kt + 1 < NT) {
      stageA(kt + 1, 0); SB0(); stageB(kt + 1, 0); SB0();
      stageA(kt + 1, 1); SB0(); stageB(kt + 1, 1); SB0();
    }
    PH_MID();
    __builtin_amdgcn_s_setprio(1);
#pragma unroll
    for (int mf = 0; mf < 4; ++mf)
#pragma unroll
      for (int nf = 0; nf < 2; ++nf) {
        acc[0][mf][0][nf] = MFMA16(af[mf][0], bv[nf][0], acc[0][mf][0][nf]);
        acc[0][mf][0][nf] = MFMA16(af[mf][1], bv[nf][1], acc[0][mf][0][nf]);
      }
    __builtin_amdgcn_s_setprio(0);
    PH_END();

    // ===== P2 (mh0,nh1): read B-h1 (4) =====
#pragma unroll
    for (int nf = 0; nf < 2; ++nf) {
      bw[nf][0] = *(const bf16x8*)(Bb + (b_rb + 16384 + nf * 2048 + sq0));
      bw[nf][1] = *(const bf16x8*)(Bb + (b_rb + 16384 + nf * 2048 + sq1));
    }
    PH_MID();
    __builtin_amdgcn_s_setprio(1);
#pragma unroll
    for (int mf = 0; mf < 4; ++mf)
#pragma unroll
      for (int nf = 0; nf < 2; ++nf) {
        acc[0][mf][1][nf] = MFMA16(af[mf][0], bw[nf][0], acc[0][mf][1][nf]);
        acc[0][mf][1][nf] = MFMA16(af[mf][1], bw[nf][1], acc[0][mf][1][nf]);
      }
    __builtin_amdgcn_s_setprio(0);
    PH_END();

    // ===== P3 (mh1,nh1): read A-h1 (8) =====
#pragma unroll
    for (int mf = 0; mf < 4; ++mf) {
      af[mf][0] = *(const bf16x8*)(Ab + (a_rb + 16384 + mf * 2048 + sq0));
      af[mf][1] = *(const bf16x8*)(Ab + (a_rb + 16384 + mf * 2048 + sq1));
    }
    PH_MID();
    __builtin_amdgcn_s_setprio(1);
#pragma unroll
    for (int mf = 0; mf < 4; ++mf)
#pragma unroll
      for (int nf = 0; nf < 2; ++nf) {
        acc[1][mf][1][nf] = MFMA16(af[mf][0], bw[nf][0], acc[1][mf][1][nf]);
        acc[1][mf][1][nf] = MFMA16(af[mf][1], bw[nf][1], acc[1][mf][1][nf]);
      }
    __builtin_amdgcn_s_setprio(0);
    PH_END();

    // ===== P4 (mh1,nh0): re-read B-h0 (4); drain kt+1's loads =====
#pragma unroll
    for (int nf = 0; nf < 2; ++nf) {
      bv[nf][0] = *(const bf16x8*)(Bb + (b_rb + nf * 2048 + sq0));
      bv[nf][1] = *(const bf16x8*)(Bb + (b_rb + nf * 2048 + sq1));
    }
    PH_MID();
    __builtin_amdgcn_s_setprio(1);
#pragma unroll
    for (int mf = 0; mf < 4; ++mf)
#pragma unroll
      for (int nf = 0; nf < 2; ++nf) {
        acc[1][mf][0][nf] = MFMA16(af[mf][0], bv[nf][0], acc[1][mf][0][nf]);
        acc[1][mf][0][nf] = MFMA16(af[mf][1], bv[nf][1], acc[1][mf][0][nf]);
      }
    __builtin_amdgcn_s_setprio(0);
    SB0();
    asm volatile("s_waitcnt vmcnt(0)" ::: "memory");  // kt+1 fully landed
    __builtin_amdgcn_s_barrier();
    SB0();
  }

  // ---- epilogue ----
#pragma unroll
  for (int mh = 0; mh < 2; ++mh)
#pragma unroll
  for (int mf = 0; mf < 4; ++mf)
#pragma unroll
  for (int nh = 0; nh < 2; ++nh)
#pragma unroll
  for (int nf = 0; nf < 2; ++nf) {
    int ncol = n0 + wn * 32 + nh * 128 + nf * 16 + l16;
    float bb = bias[ncol];
    int mbase = m0 + wm * 64 + mh * 128 + mf * 16 + quad * 4;
    if (cmode == 0) {
      int which = ncol >> 10;           // 0=Q 1=K 2=V
      int h = (ncol >> 6) & 15;
      int d = ncol & 63;
      int b_ = mbase >> 11, t = mbase & 2047;
      if (which == 2) {
        bf16x4 pk;
#pragma unroll
        for (int r = 0; r < 4; ++r) pk[r] = (bf16_t)(acc[mh][mf][nh][nf][r] + bb);
        size_t dst = 2 * HBREG + ((size_t)((b_ * 16 + h) * 64 + d)) * 2048 + t;
        *(bf16x4*)&g_qkv[dst] = pk;
      } else {
        size_t base = (size_t)which * HBREG +
                      ((size_t)((b_ * 16 + h) * 2048 + t)) * 64 + d;
#pragma unroll
        for (int r = 0; r < 4; ++r)
          g_qkv[base + (size_t)r * 64] = (bf16_t)(acc[mh][mf][nh][nf][r] + bb);
      }
    } else {
#pragma unroll
      for (int r = 0; r < 4; ++r)
        out_ext[(size_t)(mbase + r) * N + ncol] = acc[mh][mf][nh][nf][r] + bb;
    }
  }
}

// ---------------- causal flash attention, Dh=64, T=2048 ----------------
// R6 version (proven): swizzled LDS (0 pad), merged q-tile pair, one
// barrier/k-tile, bh->XCD pinned grid. Unchanged this round.
__global__ __launch_bounds__(256, 3) void attn64() {
  __shared__ bf16_t Ks[2][64 * 64];
  __shared__ bf16_t Vt[2][64 * 64];
  __shared__ bf16_t Ps[8][16 * 64];   // [wave*2 + hi/lo][16 rows x 128B]
  const float C1 = 0.1803368801111204f;    // log2(e)/8
  const float C2 = -23.083120654223414f;   // -16*log2(e)
  const int tid = threadIdx.x;
  const int qpair = blockIdx.y;            // 0..15
  const int bh = blockIdx.x;               // 0..63 (fast dim -> XCD = bh%8)
  const bf16_t* Qb  = g_qkv + (size_t)bh * 2048 * 64;
  const bf16_t* Kb  = g_qkv + HBREG + (size_t)bh * 2048 * 64;
  const bf16_t* VTb = g_qkv + 2 * HBREG + (size_t)bh * 64 * 2048;
  bf16_t* Yb = g_qkv + (size_t)bh * 2048 * 64;
  const int lane = tid & 63, wave = tid >> 6;
  const int quad = lane >> 4, l16 = lane & 15;
  const int row0 = tid >> 3, c80 = (tid & 7) * 8;   // staging coords
  char* PwH = (char*)&Ps[wave * 2 + 0][0];
  char* PwL = (char*)&Ps[wave * 2 + 1][0];

  // staging write offsets (swizzled): row*128 + (colByte ^ ((row&7)<<4))
  const int stW0 = row0 * 128 + ((c80 * 2) ^ ((row0 & 7) << 4));
  const int stW1 = stW0 + 32 * 128;        // (row0+32)&7 == row0&7
  // fragment-read slot offsets (row = tn*16 + l16 -> row&7 = l16&7)
  const int fmask = (l16 & 7) << 4;
  const int fs0 = (quad * 16) ^ fmask;
  const int fs1 = (64 + quad * 16) ^ fmask;
  // P write offsets (row = l16)
  int pwb[4];
#pragma unroll
  for (int tn = 0; tn < 4; ++tn)
    pwb[tn] = l16 * 128 + ((tn * 32 + quad * 8) ^ fmask);
  const int prd = l16 * 128;

  const int qlo = qpair, qhi = 31 - qpair;
  const int qrow_l = qlo * 64 + wave * 16 + l16;
  const int qrow_h = qhi * 64 + wave * 16 + l16;

  bf16x8 ones8;
#pragma unroll
  for (int j = 0; j < 8; ++j) ones8[j] = (bf16_t)1.0f;

  // Q rows straight to registers (B-fragment layout = Q rows).
  bf16x8 aql0 = *(const bf16x8*)&Qb[(size_t)qrow_l * 64 + quad * 8];
  bf16x8 aql1 = *(const bf16x8*)&Qb[(size_t)qrow_l * 64 + 32 + quad * 8];
  bf16x8 aqh0 = *(const bf16x8*)&Qb[(size_t)qrow_h * 64 + quad * 8];
  bf16x8 aqh1 = *(const bf16x8*)&Qb[(size_t)qrow_h * 64 + 32 + quad * 8];

  floatx4 oh[4] = {}, ol[4] = {};
  floatx4 osh = {}, osl = {};

  // prefetch k-tile 0 into regs
  bf16x8 kp0 = *(const bf16x8*)&Kb[(size_t)row0 * 64 + c80];
  bf16x8 kp1 = *(const bf16x8*)&Kb[(size_t)(row0 + 32) * 64 + c80];
  bf16x8 vp0 = *(const bf16x8*)&VTb[(size_t)row0 * 2048 + c80];
  bf16x8 vp1 = *(const bf16x8*)&VTb[(size_t)(row0 + 32) * 2048 + c80];

  const int ntiles = qhi + 1;
  int c = 0;
  for (int kt = 0; kt < ntiles; ++kt) {
    char* KsB = (char*)&Ks[c][0];
    char* VtB = (char*)&Vt[c][0];
    // ---- stage k-tile kt into buf[c] (swizzled writes) ----
    *(bf16x8*)(KsB + stW0) = kp0;
    *(bf16x8*)(KsB + stW1) = kp1;
    *(bf16x8*)(VtB + stW0) = vp0;
    *(bf16x8*)(VtB + stW1) = vp1;
    if (kt + 1 < ntiles) {
      const int k1 = (kt + 1) * 64;
      kp0 = *(const bf16x8*)&Kb[(size_t)(k1 + row0) * 64 + c80];
      kp1 = *(const bf16x8*)&Kb[(size_t)(k1 + row0 + 32) * 64 + c80];
      vp0 = *(const bf16x8*)&VTb[(size_t)row0 * 2048 + k1 + c80];
      vp1 = *(const bf16x8*)&VTb[(size_t)(row0 + 32) * 2048 + k1 + c80];
    }
    __syncthreads();  // buf[c] visible; one barrier per k-tile

    const bool lo_on = (kt <= qlo);
    const int k0 = kt * 64;

    // ---- K fragments (shared by both q-tiles) ----
    bf16x8 bk0[4], bk1[4];
#pragma unroll
    for (int tn = 0; tn < 4; ++tn) {
      int rb = (tn * 16 + l16) * 128;
      bk0[tn] = *(const bf16x8*)(KsB + rb + fs0);
      bk1[tn] = *(const bf16x8*)(KsB + rb + fs1);
    }

    // ---- QK^T swapped: lane holds q=l16, k = tn*16+quad*4+r ----
    floatx4 sh[4], sl[4];
    __builtin_amdgcn_s_setprio(1);
#pragma unroll
    for (int tn = 0; tn < 4; ++tn) {
      floatx4 z = {};
      z = __builtin_amdgcn_mfma_f32_16x16x32_bf16(bk0[tn], aqh0, z, 0, 0, 0);
      z = __builtin_amdgcn_mfma_f32_16x16x32_bf16(bk1[tn], aqh1, z, 0, 0, 0);
      sh[tn] = z;
    }
    if (lo_on) {
#pragma unroll
      for (int tn = 0; tn < 4; ++tn) {
        floatx4 z = {};
        z = __builtin_amdgcn_mfma_f32_16x16x32_bf16(bk0[tn], aql0, z, 0, 0, 0);
        z = __builtin_amdgcn_mfma_f32_16x16x32_bf16(bk1[tn], aql1, z, 0, 0, 0);
        sl[tn] = z;
      }
    }
    __builtin_amdgcn_s_setprio(0);

    // ---- V fragments (shared) ----
    bf16x8 av0[4], av1[4];
#pragma unroll
    for (int tn = 0; tn < 4; ++tn) {
      int rb = (tn * 16 + l16) * 128;
      av0[tn] = *(const bf16x8*)(VtB + rb + fs0);
      av1[tn] = *(const bf16x8*)(VtB + rb + fs1);
    }

    // ---- softmax hi + P write ----
    if (kt == qhi) {
#pragma unroll
      for (int tn = 0; tn < 4; ++tn)
#pragma unroll
        for (int r = 0; r < 4; ++r) {
          int kcol = k0 + tn * 16 + quad * 4 + r;
          float p = exp2f(fminf(fmaf(sh[tn][r], C1, C2), 30.f));
          sh[tn][r] = (kcol > qrow_h) ? 0.f : p;
        }
    } else {
#pragma unroll
      for (int tn = 0; tn < 4; ++tn)
#pragma unroll
        for (int r = 0; r < 4; ++r)
          sh[tn][r] = exp2f(fminf(fmaf(sh[tn][r], C1, C2), 30.f));
    }
#pragma unroll
    for (int tn = 0; tn < 4; ++tn) {
      bf16x4 pk;
#pragma unroll
      for (int r = 0; r < 4; ++r) pk[r] = (bf16_t)sh[tn][r];
      *(bf16x4*)(PwH + pwb[tn]) = pk;
    }

    // ---- softmax lo + P write (block-uniform guard) ----
    if (lo_on) {
      if (kt == qlo) {
#pragma unroll
        for (int tn = 0; tn < 4; ++tn)
#pragma unroll
          for (int r = 0; r < 4; ++r) {
            int kcol = k0 + tn * 16 + quad * 4 + r;
            float p = exp2f(fminf(fmaf(sl[tn][r], C1, C2), 30.f));
            sl[tn][r] = (kcol > qrow_l) ? 0.f : p;
          }
      } else {
#pragma unroll
        for (int tn = 0; tn < 4; ++tn)
#pragma unroll
          for (int r = 0; r < 4; ++r)
            sl[tn][r] = exp2f(fminf(fmaf(sl[tn][r], C1, C2), 30.f));
      }
#pragma unroll
      for (int tn = 0; tn < 4; ++tn) {
        bf16x4 pk;
#pragma unroll
        for (int r = 0; r < 4; ++r) pk[r] = (bf16_t)sl[tn][r];
        *(bf16x4*)(PwL + pwb[tn]) = pk;
      }
    }

    // ---- P re-read (same wave: DS in-order) + PV ----
    bf16x8 pph0 = *(const bf16x8*)(PwH + prd + fs0);
    bf16x8 pph1 = *(const bf16x8*)(PwH + prd + fs1);
    __builtin_amdgcn_s_setprio(1);
#pragma unroll
    for (int tn = 0; tn < 4; ++tn) {
      oh[tn] = __builtin_amdgcn_mfma_f32_16x16x32_bf16(av0[tn], pph0, oh[tn], 0, 0, 0);
      oh[tn] = __builtin_amdgcn_mfma_f32_16x16x32_bf16(av1[tn], pph1, oh[tn], 0, 0, 0);
    }
    osh = __builtin_amdgcn_mfma_f32_16x16x32_bf16(ones8, pph0, osh, 0, 0, 0);
    osh = __builtin_amdgcn_mfma_f32_16x16x32_bf16(ones8, pph1, osh, 0, 0, 0);
    __builtin_amdgcn_s_setprio(0);

    if (lo_on) {
      bf16x8 ppl0 = *(const bf16x8*)(PwL + prd + fs0);
      bf16x8 ppl1 = *(const bf16x8*)(PwL + prd + fs1);
      __builtin_amdgcn_s_setprio(1);
#pragma unroll
      for (int tn = 0; tn < 4; ++tn) {
        ol[tn] = __builtin_amdgcn_mfma_f32_16x16x32_bf16(av0[tn], ppl0, ol[tn], 0, 0, 0);
        ol[tn] = __builtin_amdgcn_mfma_f32_16x16x32_bf16(av1[tn], ppl1, ol[tn], 0, 0, 0);
      }
      osl = __builtin_amdgcn_mfma_f32_16x16x32_bf16(ones8, ppl0, osl, 0, 0, 0);
      osl = __builtin_amdgcn_mfma_f32_16x16x32_bf16(ones8, ppl1, osl, 0, 0, 0);
      __builtin_amdgcn_s_setprio(0);
    }
    c ^= 1;
  }

  // ---- epilogue: packed b64 stores, one reciprocal per tile ----
  float invh = 1.0f / osh[0];
#pragma unroll
  for (int tn = 0; tn < 4; ++tn) {
    bf16x4 yv;
#pragma unroll
    for (int r = 0; r < 4; ++r) yv[r] = (bf16_t)(oh[tn][r] * invh);
    *(bf16x4*)&Yb[(size_t)qrow_h * 64 + tn * 16 + quad * 4] = yv;
  }
  float invl = 1.0f / osl[0];
#pragma unroll
  for (int tn = 0; tn < 4; ++tn) {
    bf16x4 yv;
#pragma unroll
    for (int r = 0; r < 4; ++r) yv[r] = (bf16_t)(ol[tn][r] * invl);
    *(bf16x4*)&Yb[(size_t)qrow_l * 64 + tn * 16 + quad * 4] = yv;
  }
}

extern "C" void kernel_launch(void* const* d_in, const int* in_sizes, int n_in,
                              void* d_out, int out_size, void* d_ws, size_t ws_size,
                              hipStream_t stream) {
  const float* x      = (const float*)d_in[0];
  const float* w_qkv  = (const float*)d_in[1];
  const float* b_qkv  = (const float*)d_in[2];
  const float* w_proj = (const float*)d_in[3];
  const float* b_proj = (const float*)d_in[4];
  (void)d_ws; (void)ws_size;

  cvt_x<<<4098, 256, 0, stream>>>(x, b_qkv, b_proj);
  tr64<<<dim3(64, 16), 256, 0, stream>>>(w_qkv, w_proj);

  // QKV: M=8192, N=3072, K=1024. Grid 12x32 = 384 blocks (256-tile).
  gemm256<<<dim3(12, 32), 512, 0, stream>>>(nullptr, 8192, 3072, 1024, 0, 0, 0);

  // bh on x (fast dim) -> all 16 q-blocks of a bh share one XCD's L2.
  attn64<<<dim3(64, 16), 256, 0, stream>>>();

  // proj: M=8192, N=1024, K=1024. Grid 4x32 = 128 blocks.
  gemm256<<<dim3(4, 32), 512, 0, stream>>>((float*)d_out, 8192, 1024, 1024, 1, 1, 1);
}

// Round 8
// 285.456 us; speedup vs baseline: 1.0569x; 1.0569x over previous
//
#include <hip/hip_runtime.h>
#include <hip/hip_bf16.h>
#include <math.h>

typedef __bf16 bf16_t;
typedef __bf16 bf16x4 __attribute__((ext_vector_type(4)));
typedef __bf16 bf16x8 __attribute__((ext_vector_type(8)));
typedef float floatx4 __attribute__((ext_vector_type(4)));
typedef unsigned int u32;

#define AS1 __attribute__((address_space(1)))
#define AS3 __attribute__((address_space(3)))

// Inputs fp32, output fp32.
__device__ bf16_t g_xb[8192 * 1024];              // x converted to bf16
__device__ bf16_t g_wqkvT[3072 * 1024];           // w_qkv^T (bf16)
__device__ bf16_t g_wprojT[1024 * 1024];          // w_proj^T (bf16)
__device__ float  g_bqkv[3072];
__device__ float  g_bproj[1024];
// Region 0: Q (bh, t, d) — reused as y after attention.
// Region 1: K (bh, t, d).
// Region 2: V^T (bh, d, t).
__device__ bf16_t g_qkv[3ull * 64 * 2048 * 64];
#define HBREG (64ull * 2048 * 64)

// ---------------- prep: x convert + both bias copies in one launch --------
__global__ __launch_bounds__(256) void cvt_x(const float* __restrict__ src,
                                             const float* __restrict__ bq,
                                             const float* __restrict__ bp) {
  int blk = blockIdx.x;
  int tid = threadIdx.x;
  if (blk < 4096) {
    int i0 = (blk * 256 + tid) * 8;
    const float4* s = (const float4*)src;
    float4 a = s[i0 / 4], b = s[i0 / 4 + 1];
    bf16x8 v;
    v[0] = (bf16_t)a.x; v[1] = (bf16_t)a.y; v[2] = (bf16_t)a.z; v[3] = (bf16_t)a.w;
    v[4] = (bf16_t)b.x; v[5] = (bf16_t)b.y; v[6] = (bf16_t)b.z; v[7] = (bf16_t)b.w;
    *(bf16x8*)&g_xb[i0] = v;
  } else if (blk == 4096) {
    for (int i = tid; i < 3072; i += 256) g_bqkv[i] = bq[i];
  } else {
    for (int i = tid; i < 1024; i += 256) g_bproj[i] = bp[i];
  }
}

// ---------------- 64x64 tiled transpose, both weights in one launch -------
__global__ __launch_bounds__(256) void tr64(const float* __restrict__ wqkv,
                                            const float* __restrict__ wproj) {
  __shared__ bf16_t tile[64][65];
  const int R = 1024;
  int bx = blockIdx.x;
  const float* in;
  bf16_t* out;
  int C, c0;
  if (bx < 48) { in = wqkv; out = g_wqkvT; C = 3072; c0 = bx * 64; }
  else         { in = wproj; out = g_wprojT; C = 1024; c0 = (bx - 48) * 64; }
  int r0 = blockIdx.y * 64;
  int tid = threadIdx.x;
#pragma unroll
  for (int it = 0; it < 16; ++it) {
    int idx = tid + it * 256;
    int r = idx >> 6, c = idx & 63;
    tile[r][c] = (bf16_t)in[(size_t)(r0 + r) * C + (c0 + c)];
  }
  __syncthreads();
#pragma unroll
  for (int it = 0; it < 16; ++it) {
    int idx = tid + it * 256;
    int r = idx >> 6, c = idx & 63;
    out[(size_t)(c0 + r) * R + (r0 + c)] = tile[c][r];
  }
}

// ------------- GEMM, m201 template: C = A @ Bt^T + bias -------------------
// R8: deep-lookahead counted schedule (the actual m201 stage map).
// Stage targets: P1->(kt+1).A1, P2->(kt+1).B1, P3->(kt+2).A0, P4->(kt+2).B0.
// (kt+2) staging lands in the CURRENT buffer's h0 slots — safe: those slots'
// last ds_reads completed before their phase's lgkmcnt(0)+barrier, >=2
// barriers before the stage issues. Every half-tile is staged 4-6 phases
// before first read (>= HBM latency). B-h0 fragments stay in registers
// P1->P4 (no P4 re-read -> B0 slot dead after P1).
// Counted waits from issue order (2 loads/thread per stage):
//   P1-end vmcnt(6)  [guards kt.A1,kt.B1; 3 younger pairs in flight]
//   P4-end vmcnt(8)  [guards (kt+1).A0,B0; 4 younger pairs in flight]
// Tails: kt==NT-1 P1-end vmcnt(0); P4-end kt==NT-2 vmcnt(4), kt==NT-1 none.
// Never a mid-loop vmcnt(0) drain (R7's mistake).
#define MFMA16(a, b, c) __builtin_amdgcn_mfma_f32_16x16x32_bf16(a, b, c, 0, 0, 0)
#define SB0() __builtin_amdgcn_sched_barrier(0)
#define PH_MID()                                          \
  do {                                                    \
    SB0();                                                \
    __builtin_amdgcn_s_barrier();                         \
    SB0();                                                \
    asm volatile("s_waitcnt lgkmcnt(0)" ::: "memory");    \
    SB0();                                                \
  } while (0)
#define PH_END()                                          \
  do {                                                    \
    SB0();                                                \
    __builtin_amdgcn_s_barrier();                         \
    SB0();                                                \
  } while (0)

__global__ __launch_bounds__(512) void gemm256(float* __restrict__ out_ext,
                                               int M, int N, int K,
                                               int amode, int bsel, int cmode) {
  __shared__ alignas(16) bf16_t As[2][256 * 64];
  __shared__ alignas(16) bf16_t Bs[2][256 * 64];
  (void)M;
  const bf16_t* Ag = (amode == 0) ? g_xb : g_qkv;
  const bf16_t* Bt = bsel ? g_wprojT : g_wqkvT;
  const float* bias = bsel ? g_bproj : g_bqkv;
  const int tid = threadIdx.x;

  // XCD-aware bijective swizzle (nwg % 8 == 0 for both grids).
  int gx = gridDim.x;
  int nwg = gx * gridDim.y;
  int lin = blockIdx.y * gx + blockIdx.x;
  int swz = (lin & 7) * (nwg >> 3) + (lin >> 3);
  int bx = swz % gx, by = swz / gx;
  const int m0 = by * 256, n0 = bx * 256;

  const int lane = tid & 63, wave = tid >> 6;
  const int wm = wave >> 2, wn = wave & 3;      // 2M x 4N
  const int quad = lane >> 4, l16 = lane & 15;

  // ---- ds_read fragment addressing (swizzle: byte ^= (row&7)<<4) ----
  const u32 xv = (u32)(l16 & 7) << 4;
  const u32 sq0 = ((u32)quad * 16u) ^ xv;          // k-slab 0
  const u32 sq1 = (64u + (u32)quad * 16u) ^ xv;    // k-slab 1
  const u32 a_rb = (u32)(wm * 64 + l16) * 128u;    // + mh*16384 + mf*2048
  const u32 b_rb = (u32)(wn * 32 + l16) * 128u;    // + nh*16384 + nf*2048

  // ---- staging precompute: inverse-swizzled global source per thread ----
  u32 row_j[2], scol_j[2];
#pragma unroll
  for (int j = 0; j < 2; ++j) {
    u32 L = ((u32)j * 512u + (u32)tid) * 16u;   // LDS byte within 16KB half
    u32 y = L ^ (((L >> 7) & 7u) << 4);         // involution
    row_j[j] = y >> 7;                          // row 0..127 within half
    scol_j[j] = (y & 127u) >> 1;                // k elem 0..63
  }
  u32 a_go[2][2], b_go[2][2], akts;
  if (amode == 0) {
#pragma unroll
    for (int h = 0; h < 2; ++h)
#pragma unroll
      for (int j = 0; j < 2; ++j)
        a_go[h][j] = (u32)(m0 + h * 128 + (int)row_j[j]) * (u32)K + scol_j[j];
    akts = 64u;
  } else {
#pragma unroll
    for (int h = 0; h < 2; ++h)
#pragma unroll
      for (int j = 0; j < 2; ++j) {
        int m = m0 + h * 128 + (int)row_j[j];
        a_go[h][j] = (u32)(m >> 11) * 2097152u + (u32)(m & 2047) * 64u + scol_j[j];
      }
    akts = 131072u;   // K-tile == head stride in (bh,t,d) layout
  }
#pragma unroll
  for (int h = 0; h < 2; ++h)
#pragma unroll
    for (int j = 0; j < 2; ++j)
      b_go[h][j] = (u32)(n0 + h * 128 + (int)row_j[j]) * (u32)K + scol_j[j];

  auto stageA = [&](int kt_, int h_) {
#pragma unroll
    for (int j = 0; j < 2; ++j)
      __builtin_amdgcn_global_load_lds(
          (const AS1 void*)(Ag + (size_t)(a_go[h_][j] + (u32)kt_ * akts)),
          (AS3 void*)&As[kt_ & 1][h_ * 8192 + (j * 512 + tid) * 8], 16, 0, 0);
  };
  auto stageB = [&](int kt_, int h_) {
#pragma unroll
    for (int j = 0; j < 2; ++j)
      __builtin_amdgcn_global_load_lds(
          (const AS1 void*)(Bt + (size_t)(b_go[h_][j] + (u32)kt_ * 64u)),
          (AS3 void*)&Bs[kt_ & 1][h_ * 8192 + (j * 512 + tid) * 8], 16, 0, 0);
  };

  floatx4 acc[2][4][2][2] = {};   // [mh][mf][nh][nf]
  const int NT = K >> 6;

  // ---- prologue: tile0 all 4 halves + tile1 A0,B0; guard tile0 h0 ----
  stageA(0, 0); SB0(); stageB(0, 0); SB0();
  stageA(0, 1); SB0(); stageB(0, 1); SB0();
  stageA(1, 0); SB0(); stageB(1, 0); SB0();
  asm volatile("s_waitcnt vmcnt(8)" ::: "memory");  // 0.A0,0.B0 landed
  __builtin_amdgcn_s_barrier();
  SB0();

  for (int kt = 0; kt < NT; ++kt) {
    const int b = kt & 1;
    const char* Ab = (const char*)&As[b][0];
    const char* Bb = (const char*)&Bs[b][0];
    bf16x8 af[4][2], bv[2][2], bw[2][2];

    // ===== P1 (mh0,nh0): read A-h0 (8) + B-h0 (4); stage (kt+1).A1 =====
#pragma unroll
    for (int mf = 0; mf < 4; ++mf) {
      af[mf][0] = *(const bf16x8*)(Ab + (a_rb + mf * 2048 + sq0));
      af[mf][1] = *(const bf16x8*)(Ab + (a_rb + mf * 2048 + sq1));
    }
#pragma unroll
    for (int nf = 0; nf < 2; ++nf) {
      bv[nf][0] = *(const bf16x8*)(Bb + (b_rb + nf * 2048 + sq0));
      bv[nf][1] = *(const bf16x8*)(Bb + (b_rb + nf * 2048 + sq1));
    }
    if (kt + 1 < NT) stageA(kt + 1, 1);
    PH_MID();
    __builtin_amdgcn_s_setprio(1);
#pragma unroll
    for (int mf = 0; mf < 4; ++mf)
#pragma unroll
      for (int nf = 0; nf < 2; ++nf) {
        acc[0][mf][0][nf] = MFMA16(af[mf][0], bv[nf][0], acc[0][mf][0][nf]);
        acc[0][mf][0][nf] = MFMA16(af[mf][1], bv[nf][1], acc[0][mf][0][nf]);
      }
    __builtin_amdgcn_s_setprio(0);
    SB0();
    if (kt + 1 < NT) asm volatile("s_waitcnt vmcnt(6)" ::: "memory");
    else             asm volatile("s_waitcnt vmcnt(0)" ::: "memory");
    __builtin_amdgcn_s_barrier();
    SB0();

    // ===== P2 (mh0,nh1): read B-h1 (4); stage (kt+1).B1 =====
#pragma unroll
    for (int nf = 0; nf < 2; ++nf) {
      bw[nf][0] = *(const bf16x8*)(Bb + (b_rb + 16384 + nf * 2048 + sq0));
      bw[nf][1] = *(const bf16x8*)(Bb + (b_rb + 16384 + nf * 2048 + sq1));
    }
    if (kt + 1 < NT) stageB(kt + 1, 1);
    PH_MID();
    __builtin_amdgcn_s_setprio(1);
#pragma unroll
    for (int mf = 0; mf < 4; ++mf)
#pragma unroll
      for (int nf = 0; nf < 2; ++nf) {
        acc[0][mf][1][nf] = MFMA16(af[mf][0], bw[nf][0], acc[0][mf][1][nf]);
        acc[0][mf][1][nf] = MFMA16(af[mf][1], bw[nf][1], acc[0][mf][1][nf]);
      }
    __builtin_amdgcn_s_setprio(0);
    PH_END();

    // ===== P3 (mh1,nh1): read A-h1 (8); stage (kt+2).A0 (current buf) =====
#pragma unroll
    for (int mf = 0; mf < 4; ++mf) {
      af[mf][0] = *(const bf16x8*)(Ab + (a_rb + 16384 + mf * 2048 + sq0));
      af[mf][1] = *(const bf16x8*)(Ab + (a_rb + 16384 + mf * 2048 + sq1));
    }
    if (kt + 2 < NT) stageA(kt + 2, 0);
    PH_MID();
    __builtin_amdgcn_s_setprio(1);
#pragma unroll
    for (int mf = 0; mf < 4; ++mf)
#pragma unroll
      for (int nf = 0; nf < 2; ++nf) {
        acc[1][mf][1][nf] = MFMA16(af[mf][0], bw[nf][0], acc[1][mf][1][nf]);
        acc[1][mf][1][nf] = MFMA16(af[mf][1], bw[nf][1], acc[1][mf][1][nf]);
      }
    __builtin_amdgcn_s_setprio(0);
    PH_END();

    // ===== P4 (mh1,nh0): bv kept in regs; stage (kt+2).B0 (current buf) ====
    if (kt + 2 < NT) stageB(kt + 2, 0);
    PH_MID();
    __builtin_amdgcn_s_setprio(1);
#pragma unroll
    for (int mf = 0; mf < 4; ++mf)
#pragma unroll
      for (int nf = 0; nf < 2; ++nf) {
        acc[1][mf][0][nf] = MFMA16(af[mf][0], bv[nf][0], acc[1][mf][0][nf]);
        acc[1][mf][0][nf] = MFMA16(af[mf][1], bv[nf][1], acc[1][mf][0][nf]);
      }
    __builtin_amdgcn_s_setprio(0);
    SB0();
    if (kt + 2 < NT)      asm volatile("s_waitcnt vmcnt(8)" ::: "memory");
    else if (kt + 1 < NT) asm volatile("s_waitcnt vmcnt(4)" ::: "memory");
    __builtin_amdgcn_s_barrier();
    SB0();
  }

  // ---- epilogue ----
#pragma unroll
  for (int mh = 0; mh < 2; ++mh)
#pragma unroll
  for (int mf = 0; mf < 4; ++mf)
#pragma unroll
  for (int nh = 0; nh < 2; ++nh)
#pragma unroll
  for (int nf = 0; nf < 2; ++nf) {
    int ncol = n0 + wn * 32 + nh * 128 + nf * 16 + l16;
    float bb = bias[ncol];
    int mbase = m0 + wm * 64 + mh * 128 + mf * 16 + quad * 4;
    if (cmode == 0) {
      int which = ncol >> 10;           // 0=Q 1=K 2=V
      int h = (ncol >> 6) & 15;
      int d = ncol & 63;
      int b_ = mbase >> 11, t = mbase & 2047;
      if (which == 2) {
        bf16x4 pk;
#pragma unroll
        for (int r = 0; r < 4; ++r) pk[r] = (bf16_t)(acc[mh][mf][nh][nf][r] + bb);
        size_t dst = 2 * HBREG + ((size_t)((b_ * 16 + h) * 64 + d)) * 2048 + t;
        *(bf16x4*)&g_qkv[dst] = pk;
      } else {
        size_t base = (size_t)which * HBREG +
                      ((size_t)((b_ * 16 + h) * 2048 + t)) * 64 + d;
#pragma unroll
        for (int r = 0; r < 4; ++r)
          g_qkv[base + (size_t)r * 64] = (bf16_t)(acc[mh][mf][nh][nf][r] + bb);
      }
    } else {
#pragma unroll
      for (int r = 0; r < 4; ++r)
        out_ext[(size_t)(mbase + r) * N + ncol] = acc[mh][mf][nh][nf][r] + bb;
    }
  }
}

// ---------------- causal flash attention, Dh=64, T=2048 ----------------
// R6 version (proven): swizzled LDS (0 pad), merged q-tile pair, one
// barrier/k-tile, bh->XCD pinned grid. Unchanged.
__global__ __launch_bounds__(256, 3) void attn64() {
  __shared__ bf16_t Ks[2][64 * 64];
  __shared__ bf16_t Vt[2][64 * 64];
  __shared__ bf16_t Ps[8][16 * 64];   // [wave*2 + hi/lo][16 rows x 128B]
  const float C1 = 0.1803368801111204f;    // log2(e)/8
  const float C2 = -23.083120654223414f;   // -16*log2(e)
  const int tid = threadIdx.x;
  const int qpair = blockIdx.y;            // 0..15
  const int bh = blockIdx.x;               // 0..63 (fast dim -> XCD = bh%8)
  const bf16_t* Qb  = g_qkv + (size_t)bh * 2048 * 64;
  const bf16_t* Kb  = g_qkv + HBREG + (size_t)bh * 2048 * 64;
  const bf16_t* VTb = g_qkv + 2 * HBREG + (size_t)bh * 64 * 2048;
  bf16_t* Yb = g_qkv + (size_t)bh * 2048 * 64;
  const int lane = tid & 63, wave = tid >> 6;
  const int quad = lane >> 4, l16 = lane & 15;
  const int row0 = tid >> 3, c80 = (tid & 7) * 8;   // staging coords
  char* PwH = (char*)&Ps[wave * 2 + 0][0];
  char* PwL = (char*)&Ps[wave * 2 + 1][0];

  // staging write offsets (swizzled): row*128 + (colByte ^ ((row&7)<<4))
  const int stW0 = row0 * 128 + ((c80 * 2) ^ ((row0 & 7) << 4));
  const int stW1 = stW0 + 32 * 128;        // (row0+32)&7 == row0&7
  // fragment-read slot offsets (row = tn*16 + l16 -> row&7 = l16&7)
  const int fmask = (l16 & 7) << 4;
  const int fs0 = (quad * 16) ^ fmask;
  const int fs1 = (64 + quad * 16) ^ fmask;
  // P write offsets (row = l16)
  int pwb[4];
#pragma unroll
  for (int tn = 0; tn < 4; ++tn)
    pwb[tn] = l16 * 128 + ((tn * 32 + quad * 8) ^ fmask);
  const int prd = l16 * 128;

  const int qlo = qpair, qhi = 31 - qpair;
  const int qrow_l = qlo * 64 + wave * 16 + l16;
  const int qrow_h = qhi * 64 + wave * 16 + l16;

  bf16x8 ones8;
#pragma unroll
  for (int j = 0; j < 8; ++j) ones8[j] = (bf16_t)1.0f;

  // Q rows straight to registers (B-fragment layout = Q rows).
  bf16x8 aql0 = *(const bf16x8*)&Qb[(size_t)qrow_l * 64 + quad * 8];
  bf16x8 aql1 = *(const bf16x8*)&Qb[(size_t)qrow_l * 64 + 32 + quad * 8];
  bf16x8 aqh0 = *(const bf16x8*)&Qb[(size_t)qrow_h * 64 + quad * 8];
  bf16x8 aqh1 = *(const bf16x8*)&Qb[(size_t)qrow_h * 64 + 32 + quad * 8];

  floatx4 oh[4] = {}, ol[4] = {};
  floatx4 osh = {}, osl = {};

  // prefetch k-tile 0 into regs
  bf16x8 kp0 = *(const bf16x8*)&Kb[(size_t)row0 * 64 + c80];
  bf16x8 kp1 = *(const bf16x8*)&Kb[(size_t)(row0 + 32) * 64 + c80];
  bf16x8 vp0 = *(const bf16x8*)&VTb[(size_t)row0 * 2048 + c80];
  bf16x8 vp1 = *(const bf16x8*)&VTb[(size_t)(row0 + 32) * 2048 + c80];

  const int ntiles = qhi + 1;
  int c = 0;
  for (int kt = 0; kt < ntiles; ++kt) {
    char* KsB = (char*)&Ks[c][0];
    char* VtB = (char*)&Vt[c][0];
    // ---- stage k-tile kt into buf[c] (swizzled writes) ----
    *(bf16x8*)(KsB + stW0) = kp0;
    *(bf16x8*)(KsB + stW1) = kp1;
    *(bf16x8*)(VtB + stW0) = vp0;
    *(bf16x8*)(VtB + stW1) = vp1;
    if (kt + 1 < ntiles) {
      const int k1 = (kt + 1) * 64;
      kp0 = *(const bf16x8*)&Kb[(size_t)(k1 + row0) * 64 + c80];
      kp1 = *(const bf16x8*)&Kb[(size_t)(k1 + row0 + 32) * 64 + c80];
      vp0 = *(const bf16x8*)&VTb[(size_t)row0 * 2048 + k1 + c80];
      vp1 = *(const bf16x8*)&VTb[(size_t)(row0 + 32) * 2048 + k1 + c80];
    }
    __syncthreads();  // buf[c] visible; one barrier per k-tile

    const bool lo_on = (kt <= qlo);
    const int k0 = kt * 64;

    // ---- K fragments (shared by both q-tiles) ----
    bf16x8 bk0[4], bk1[4];
#pragma unroll
    for (int tn = 0; tn < 4; ++tn) {
      int rb = (tn * 16 + l16) * 128;
      bk0[tn] = *(const bf16x8*)(KsB + rb + fs0);
      bk1[tn] = *(const bf16x8*)(KsB + rb + fs1);
    }

    // ---- QK^T swapped: lane holds q=l16, k = tn*16+quad*4+r ----
    floatx4 sh[4], sl[4];
    __builtin_amdgcn_s_setprio(1);
#pragma unroll
    for (int tn = 0; tn < 4; ++tn) {
      floatx4 z = {};
      z = __builtin_amdgcn_mfma_f32_16x16x32_bf16(bk0[tn], aqh0, z, 0, 0, 0);
      z = __builtin_amdgcn_mfma_f32_16x16x32_bf16(bk1[tn], aqh1, z, 0, 0, 0);
      sh[tn] = z;
    }
    if (lo_on) {
#pragma unroll
      for (int tn = 0; tn < 4; ++tn) {
        floatx4 z = {};
        z = __builtin_amdgcn_mfma_f32_16x16x32_bf16(bk0[tn], aql0, z, 0, 0, 0);
        z = __builtin_amdgcn_mfma_f32_16x16x32_bf16(bk1[tn], aql1, z, 0, 0, 0);
        sl[tn] = z;
      }
    }
    __builtin_amdgcn_s_setprio(0);

    // ---- V fragments (shared) ----
    bf16x8 av0[4], av1[4];
#pragma unroll
    for (int tn = 0; tn < 4; ++tn) {
      int rb = (tn * 16 + l16) * 128;
      av0[tn] = *(const bf16x8*)(VtB + rb + fs0);
      av1[tn] = *(const bf16x8*)(VtB + rb + fs1);
    }

    // ---- softmax hi + P write ----
    if (kt == qhi) {
#pragma unroll
      for (int tn = 0; tn < 4; ++tn)
#pragma unroll
        for (int r = 0; r < 4; ++r) {
          int kcol = k0 + tn * 16 + quad * 4 + r;
          float p = exp2f(fminf(fmaf(sh[tn][r], C1, C2), 30.f));
          sh[tn][r] = (kcol > qrow_h) ? 0.f : p;
        }
    } else {
#pragma unroll
      for (int tn = 0; tn < 4; ++tn)
#pragma unroll
        for (int r = 0; r < 4; ++r)
          sh[tn][r] = exp2f(fminf(fmaf(sh[tn][r], C1, C2), 30.f));
    }
#pragma unroll
    for (int tn = 0; tn < 4; ++tn) {
      bf16x4 pk;
#pragma unroll
      for (int r = 0; r < 4; ++r) pk[r] = (bf16_t)sh[tn][r];
      *(bf16x4*)(PwH + pwb[tn]) = pk;
    }

    // ---- softmax lo + P write (block-uniform guard) ----
    if (lo_on) {
      if (kt == qlo) {
#pragma unroll
        for (int tn = 0; tn < 4; ++tn)
#pragma unroll
          for (int r = 0; r < 4; ++r) {
            int kcol = k0 + tn * 16 + quad * 4 + r;
            float p = exp2f(fminf(fmaf(sl[tn][r], C1, C2), 30.f));
            sl[tn][r] = (kcol > qrow_l) ? 0.f : p;
          }
      } else {
#pragma unroll
        for (int tn = 0; tn < 4; ++tn)
#pragma unroll
          for (int r = 0; r < 4; ++r)
            sl[tn][r] = exp2f(fminf(fmaf(sl[tn][r], C1, C2), 30.f));
      }
#pragma unroll
      for (int tn = 0; tn < 4; ++tn) {
        bf16x4 pk;
#pragma unroll
        for (int r = 0; r < 4; ++r) pk[r] = (bf16_t)sl[tn][r];
        *(bf16x4*)(PwL + pwb[tn]) = pk;
      }
    }

    // ---- P re-read (same wave: DS in-order) + PV ----
    bf16x8 pph0 = *(const bf16x8*)(PwH + prd + fs0);
    bf16x8 pph1 = *(const bf16x8*)(PwH + prd + fs1);
    __builtin_amdgcn_s_setprio(1);
#pragma unroll
    for (int tn = 0; tn < 4; ++tn) {
      oh[tn] = __builtin_amdgcn_mfma_f32_16x16x32_bf16(av0[tn], pph0, oh[tn], 0, 0, 0);
      oh[tn] = __builtin_amdgcn_mfma_f32_16x16x32_bf16(av1[tn], pph1, oh[tn], 0, 0, 0);
    }
    osh = __builtin_amdgcn_mfma_f32_16x16x32_bf16(ones8, pph0, osh, 0, 0, 0);
    osh = __builtin_amdgcn_mfma_f32_16x16x32_bf16(ones8, pph1, osh, 0, 0, 0);
    __builtin_amdgcn_s_setprio(0);

    if (lo_on) {
      bf16x8 ppl0 = *(const bf16x8*)(PwL + prd + fs0);
      bf16x8 ppl1 = *(const bf16x8*)(PwL + prd + fs1);
      __builtin_amdgcn_s_setprio(1);
#pragma unroll
      for (int tn = 0; tn < 4; ++tn) {
        ol[tn] = __builtin_amdgcn_mfma_f32_16x16x32_bf16(av0[tn], ppl0, ol[tn], 0, 0, 0);
        ol[tn] = __builtin_amdgcn_mfma_f32_16x16x32_bf16(av1[tn], ppl1, ol[tn], 0, 0, 0);
      }
      osl = __builtin_amdgcn_mfma_f32_16x16x32_bf16(ones8, ppl0, osl, 0, 0, 0);
      osl = __builtin_amdgcn_mfma_f32_16x16x32_bf16(ones8, ppl1, osl, 0, 0, 0);
      __builtin_amdgcn_s_setprio(0);
    }
    c ^= 1;
  }

  // ---- epilogue: packed b64 stores, one reciprocal per tile ----
  float invh = 1.0f / osh[0];
#pragma unroll
  for (int tn = 0; tn < 4; ++tn) {
    bf16x4 yv;
#pragma unroll
    for (int r = 0; r < 4; ++r) yv[r] = (bf16_t)(oh[tn][r] * invh);
    *(bf16x4*)&Yb[(size_t)qrow_h * 64 + tn * 16 + quad * 4] = yv;
  }
  float invl = 1.0f / osl[0];
#pragma unroll
  for (int tn = 0; tn < 4; ++tn) {
    bf16x4 yv;
#pragma unroll
    for (int r = 0; r < 4; ++r) yv[r] = (bf16_t)(ol[tn][r] * invl);
    *(bf16x4*)&Yb[(size_t)qrow_l * 64 + tn * 16 + quad * 4] = yv;
  }
}

extern "C" void kernel_launch(void* const* d_in, const int* in_sizes, int n_in,
                              void* d_out, int out_size, void* d_ws, size_t ws_size,
                              hipStream_t stream) {
  const float* x      = (const float*)d_in[0];
  const float* w_qkv  = (const float*)d_in[1];
  const float* b_qkv  = (const float*)d_in[2];
  const float* w_proj = (const float*)d_in[3];
  const float* b_proj = (const float*)d_in[4];
  (void)d_ws; (void)ws_size;

  cvt_x<<<4098, 256, 0, stream>>>(x, b_qkv, b_proj);
  tr64<<<dim3(64, 16), 256, 0, stream>>>(w_qkv, w_proj);

  // QKV: M=8192, N=3072, K=1024. Grid 12x32 = 384 blocks (256-tile).
  gemm256<<<dim3(12, 32), 512, 0, stream>>>(nullptr, 8192, 3072, 1024, 0, 0, 0);

  // bh on x (fast dim) -> all 16 q-blocks of a bh share one XCD's L2.
  attn64<<<dim3(64, 16), 256, 0, stream>>>();

  // proj: M=8192, N=1024, K=1024. Grid 4x32 = 128 blocks.
  gemm256<<<dim3(4, 32), 512, 0, stream>>>((float*)d_out, 8192, 1024, 1024, 1, 1, 1);
}